// Round 1
// baseline (822.877 us; speedup 1.0000x reference)
//
#include <hip/hip_runtime.h>
#include <math.h>

#define NTOK 4096   // B*T = 2*2048
#define DM   1024   // d_model
#define DH   4096   // d_hid
#define NE   8      // experts
#define NSLOT (NTOK*2)

typedef unsigned short u16;
typedef __attribute__((ext_vector_type(8))) short shortx8;  // 8 bf16 (4 VGPRs)
typedef __attribute__((ext_vector_type(4))) float floatx4;
typedef __attribute__((ext_vector_type(4))) int   intx4;

__device__ __forceinline__ u16 f2bf(float f) {
  union { float f; unsigned u; } c; c.f = f;
  unsigned r = c.u + 0x7fffu + ((c.u >> 16) & 1u);   // RNE
  return (u16)(r >> 16);
}

// ---------------- x -> bf16 ----------------
__global__ void cvt_x_kernel(const float* __restrict__ x, u16* __restrict__ xb) {
  int i = (blockIdx.x * 256 + threadIdx.x) * 8;
  float4 v0 = *(const float4*)(x + i);
  float4 v1 = *(const float4*)(x + i + 4);
  u16 tmp[8] = {f2bf(v0.x), f2bf(v0.y), f2bf(v0.z), f2bf(v0.w),
                f2bf(v1.x), f2bf(v1.y), f2bf(v1.z), f2bf(v1.w)};
  *(intx4*)(xb + i) = *(intx4*)tmp;
}

// ---------------- W [E][K][NW] fp32 -> Wt [E][NW][K] bf16 ----------------
template<int K, int NW>
__global__ void transpose_kernel(const float* __restrict__ W, u16* __restrict__ Wt) {
  int e = blockIdx.z;
  const float* Wp = W + (size_t)e * K * NW;
  u16* Wtp = Wt + (size_t)e * K * NW;
  int n = blockIdx.x * 64 + (threadIdx.x & 63);
  int kend = blockIdx.y * 256 + 256;
  for (int k0 = blockIdx.y * 256 + (threadIdx.x >> 6) * 8; k0 < kend; k0 += 32) {
    u16 tmp[8];
#pragma unroll
    for (int j = 0; j < 8; j++) tmp[j] = f2bf(Wp[(size_t)(k0 + j) * NW + n]);
    *(intx4*)(Wtp + (size_t)n * K + k0) = *(intx4*)tmp;  // 16B, aligned
  }
}

// ---------------- router: logits -> top2 -> renorm softmax ----------------
__global__ void router_kernel(const float* __restrict__ x, const float* __restrict__ gw,
                              int* __restrict__ expert_of_slot, float* __restrict__ w_of_slot,
                              int* __restrict__ cnt) {
  int n = blockIdx.x;
  int lane = threadIdx.x;   // 64
  const float* xr = x + (size_t)n * DM;
  float acc[NE];
#pragma unroll
  for (int e = 0; e < NE; e++) acc[e] = 0.f;
  for (int d = lane; d < DM; d += 64) {
    float xv = xr[d];
#pragma unroll
    for (int e = 0; e < NE; e++) acc[e] += xv * gw[e * DM + d];
  }
#pragma unroll
  for (int e = 0; e < NE; e++) {
    float v = acc[e];
#pragma unroll
    for (int off = 32; off > 0; off >>= 1) v += __shfl_xor(v, off, 64);
    acc[e] = v;
  }
  if (lane == 0) {
    int i0 = 0;
    for (int e = 1; e < NE; e++) if (acc[e] > acc[i0]) i0 = e;
    int i1 = (i0 == 0) ? 1 : 0;
    for (int e = 0; e < NE; e++) { if (e == i0) continue; if (acc[e] > acc[i1]) i1 = e; }
    // renormalized top-2 softmax == pairwise softmax (Z cancels)
    float e1 = expf(acc[i1] - acc[i0]);
    float w0 = 1.f / (1.f + e1);
    expert_of_slot[2 * n] = i0;  expert_of_slot[2 * n + 1] = i1;
    w_of_slot[2 * n] = w0;       w_of_slot[2 * n + 1] = 1.f - w0;
    atomicAdd(&cnt[i0], 1);      atomicAdd(&cnt[i1], 1);
  }
}

__global__ void scan_kernel(const int* __restrict__ cnt, int* __restrict__ goff,
                            int* __restrict__ cursor) {
  if (threadIdx.x == 0) {
    int o = 0;
    for (int e = 0; e < NE; e++) { goff[e] = o; o += cnt[e]; cursor[e] = 0; }
    goff[NE] = o;
  }
}

__global__ void assign_kernel(const int* __restrict__ expert_of_slot,
                              const float* __restrict__ w_of_slot,
                              const int* __restrict__ goff, int* __restrict__ cursor,
                              int* __restrict__ tok_of_g, float* __restrict__ w_of_g) {
  int s = blockIdx.x * 256 + threadIdx.x;
  if (s >= NSLOT) return;
  int e = expert_of_slot[s];
  int pos = atomicAdd(&cursor[e], 1);
  int g = goff[e] + pos;
  tok_of_g[g] = s >> 1;
  w_of_g[g] = w_of_slot[s];
}

// ---------------- grouped GEMM: 128x128 tile, BK=32, 4 waves (2x2) ----------------
// MODE 0: A=xb gathered rows, epilogue gelu -> h (bf16)
// MODE 1: A=h contiguous rows, epilogue gate-weighted atomicAdd -> out (fp32)
template<int K, int NOUT, int MODE>
__global__ __launch_bounds__(256) void moe_gemm(
    const u16* __restrict__ A, const u16* __restrict__ Wt, const float* __restrict__ bias,
    const int* __restrict__ cnt, const int* __restrict__ goff,
    const int* __restrict__ tok_of_g, const float* __restrict__ w_of_g,
    u16* __restrict__ Hout, float* __restrict__ Out) {
  int e = blockIdx.z;
  int cntE = cnt[e];
  int m0 = blockIdx.y * 128;
  if (m0 >= cntE) return;
  int mvalid = cntE - m0; if (mvalid > 128) mvalid = 128;
  int gbase = goff[e] + m0;
  int n0 = blockIdx.x * 128;
  int tid = threadIdx.x;

  __shared__ u16 As[128 * 40];   // stride 40 elems (pad 8): 2-way bank alias only
  __shared__ u16 Bs[128 * 40];

  // staging: 512 int4 chunks; thread owns chunks tid and tid+256
  int r1 = tid >> 2, c1 = tid & 3;
  int r2 = r1 + 64;
  int ar1 = (r1 < mvalid) ? r1 : (mvalid - 1);
  int ar2 = (r2 < mvalid) ? r2 : (mvalid - 1);
  const u16 *arow1, *arow2;
  if (MODE == 0) {
    arow1 = A + (size_t)tok_of_g[gbase + ar1] * K;
    arow2 = A + (size_t)tok_of_g[gbase + ar2] * K;
  } else {
    arow1 = A + (size_t)(gbase + ar1) * K;
    arow2 = A + (size_t)(gbase + ar2) * K;
  }
  const u16* wte = Wt + (size_t)e * NOUT * K;
  const u16* brow1 = wte + (size_t)(n0 + r1) * K;
  const u16* brow2 = wte + (size_t)(n0 + r2) * K;
  int coff = c1 * 8;

  int lane = tid & 63, wave = tid >> 6;
  int wm = wave >> 1, wn = wave & 1;
  int lr = lane & 15, lk = (lane >> 4) * 8;

  floatx4 acc[4][4];
#pragma unroll
  for (int i = 0; i < 4; i++)
#pragma unroll
    for (int j = 0; j < 4; j++) acc[i][j] = (floatx4){0.f, 0.f, 0.f, 0.f};

  for (int k0 = 0; k0 < K; k0 += 32) {
    intx4 av1 = *(const intx4*)(arow1 + k0 + coff);
    intx4 av2 = *(const intx4*)(arow2 + k0 + coff);
    intx4 bv1 = *(const intx4*)(brow1 + k0 + coff);
    intx4 bv2 = *(const intx4*)(brow2 + k0 + coff);
    __syncthreads();
    *(intx4*)&As[r1 * 40 + coff] = av1;
    *(intx4*)&As[r2 * 40 + coff] = av2;
    *(intx4*)&Bs[r1 * 40 + coff] = bv1;
    *(intx4*)&Bs[r2 * 40 + coff] = bv2;
    __syncthreads();
    shortx8 af[4], bfr[4];
#pragma unroll
    for (int i = 0; i < 4; i++) {
      af[i]  = *(const shortx8*)&As[(wm * 64 + i * 16 + lr) * 40 + lk];
      bfr[i] = *(const shortx8*)&Bs[(wn * 64 + i * 16 + lr) * 40 + lk];
    }
#pragma unroll
    for (int i = 0; i < 4; i++)
#pragma unroll
      for (int j = 0; j < 4; j++)
        acc[i][j] = __builtin_amdgcn_mfma_f32_16x16x32_bf16(af[i], bfr[j], acc[i][j], 0, 0, 0);
  }

  const float* bp = bias + (size_t)e * NOUT + n0;
  if (MODE == 0) {
#pragma unroll
    for (int i = 0; i < 4; i++) {
      int rowb = wm * 64 + i * 16 + (lane >> 4) * 4;
#pragma unroll
      for (int r = 0; r < 4; r++) {
        int grow = rowb + r;
        if (grow < mvalid) {
          size_t base = (size_t)(gbase + grow) * NOUT + n0;
#pragma unroll
          for (int j = 0; j < 4; j++) {
            int col = wn * 64 + j * 16 + lr;
            float v = acc[i][j][r] + bp[col];
            v = 0.5f * v * (1.f + erff(v * 0.70710678118654752f));  // exact gelu
            Hout[base + col] = f2bf(v);
          }
        }
      }
    }
  } else {
#pragma unroll
    for (int i = 0; i < 4; i++) {
      int rowb = wm * 64 + i * 16 + (lane >> 4) * 4;
#pragma unroll
      for (int r = 0; r < 4; r++) {
        int grow = rowb + r;
        if (grow < mvalid) {
          int gi = gbase + grow;
          int t = tok_of_g[gi];
          float wg = w_of_g[gi];
          float* orow = Out + (size_t)t * DM + n0;
#pragma unroll
          for (int j = 0; j < 4; j++) {
            int col = wn * 64 + j * 16 + lr;
            atomicAdd(&orow[col], wg * (acc[i][j][r] + bp[col]));
          }
        }
      }
    }
  }
}

extern "C" void kernel_launch(void* const* d_in, const int* in_sizes, int n_in,
                              void* d_out, int out_size, void* d_ws, size_t ws_size,
                              hipStream_t stream) {
  const float* x  = (const float*)d_in[0];
  const float* gw = (const float*)d_in[1];
  const float* w1 = (const float*)d_in[2];
  const float* b1 = (const float*)d_in[3];
  const float* w2 = (const float*)d_in[4];
  const float* b2 = (const float*)d_in[5];
  float* out = (float*)d_out;
  char* ws = (char*)d_ws;

  // workspace layout (~142.8 MB): w2t reuses w1t region (dead after GEMM1)
  u16* xb = (u16*)(ws + 0);                       // 8 MB
  u16* wt = (u16*)(ws + 8388608);                 // 64 MB (w1t, then w2t)
  u16* h  = (u16*)(ws + 75497472);                // 64 MB
  char* meta = ws + 142606336;
  int*   expert_of_slot = (int*)(meta);
  int*   tok_of_g       = (int*)(meta + 32768);
  float* w_of_slot      = (float*)(meta + 65536);
  float* w_of_g         = (float*)(meta + 98304);
  int*   cnt            = (int*)(meta + 131072);
  int*   goff           = (int*)(meta + 131136);
  int*   cursor         = (int*)(meta + 131264);

  hipMemsetAsync(out, 0, (size_t)NTOK * DM * 4, stream);
  hipMemsetAsync(meta + 131072, 0, 256, stream);  // cnt/goff/cursor

  cvt_x_kernel<<<NTOK * DM / 8 / 256, 256, 0, stream>>>(x, xb);
  transpose_kernel<DM, DH><<<dim3(DH / 64, DM / 256, NE), 256, 0, stream>>>(w1, wt);
  router_kernel<<<NTOK, 64, 0, stream>>>(x, gw, expert_of_slot, w_of_slot, cnt);
  scan_kernel<<<1, 64, 0, stream>>>(cnt, goff, cursor);
  assign_kernel<<<NSLOT / 256, 256, 0, stream>>>(expert_of_slot, w_of_slot, goff, cursor,
                                                 tok_of_g, w_of_g);
  moe_gemm<DM, DH, 0><<<dim3(DH / 128, NTOK / 128, NE), 256, 0, stream>>>(
      xb, wt, b1, cnt, goff, tok_of_g, w_of_g, h, nullptr);
  transpose_kernel<DH, DM><<<dim3(DM / 64, DH / 256, NE), 256, 0, stream>>>(w2, wt);
  moe_gemm<DH, DM, 1><<<dim3(DM / 128, NTOK / 128, NE), 256, 0, stream>>>(
      h, wt, b2, cnt, goff, tok_of_g, w_of_g, nullptr, out);
}

// Round 2
// 693.448 us; speedup vs baseline: 1.1866x; 1.1866x over previous
//
#include <hip/hip_runtime.h>
#include <math.h>

#define NTOK 4096   // B*T = 2*2048
#define DM   1024
#define DH   4096
#define NE   8
#define NSLOT (NTOK*2)

typedef unsigned short u16;
typedef __attribute__((ext_vector_type(8))) short shortx8;  // 8 bf16
typedef __attribute__((ext_vector_type(4))) float floatx4;
typedef __attribute__((ext_vector_type(4))) int   intx4;

__device__ __forceinline__ u16 f2bf(float f) {
  union { float f; unsigned u; } c; c.f = f;
  unsigned r = c.u + 0x7fffu + ((c.u >> 16) & 1u);   // RNE
  return (u16)(r >> 16);
}

// async 16B/lane global -> LDS (dest is wave-uniform base + lane*16)
__device__ __forceinline__ void async_cp16(const u16* g, u16* l) {
  __builtin_amdgcn_global_load_lds(
      (const __attribute__((address_space(1))) void*)g,
      (__attribute__((address_space(3))) void*)l, 16, 0, 0);
}

// ---------------- x -> bf16 ----------------
__global__ void cvt_x_kernel(const float* __restrict__ x, u16* __restrict__ xb) {
  int i = (blockIdx.x * 256 + threadIdx.x) * 8;
  float4 v0 = *(const float4*)(x + i);
  float4 v1 = *(const float4*)(x + i + 4);
  u16 tmp[8] = {f2bf(v0.x), f2bf(v0.y), f2bf(v0.z), f2bf(v0.w),
                f2bf(v1.x), f2bf(v1.y), f2bf(v1.z), f2bf(v1.w)};
  *(intx4*)(xb + i) = *(intx4*)tmp;
}

// ---------------- W [E][K][NW] fp32 -> Wt [E][NW][K] bf16 ----------------
template<int K, int NW>
__global__ void transpose_kernel(const float* __restrict__ W, u16* __restrict__ Wt) {
  int e = blockIdx.z;
  const float* Wp = W + (size_t)e * K * NW;
  u16* Wtp = Wt + (size_t)e * K * NW;
  int n = blockIdx.x * 64 + (threadIdx.x & 63);
  int kend = blockIdx.y * 256 + 256;
  for (int k0 = blockIdx.y * 256 + (threadIdx.x >> 6) * 8; k0 < kend; k0 += 32) {
    u16 tmp[8];
#pragma unroll
    for (int j = 0; j < 8; j++) tmp[j] = f2bf(Wp[(size_t)(k0 + j) * NW + n]);
    *(intx4*)(Wtp + (size_t)n * K + k0) = *(intx4*)tmp;
  }
}

// ---------------- router: logits -> top2 -> renorm softmax (no atomics) ----------------
__global__ __launch_bounds__(256) void router_kernel(const float* __restrict__ x,
                                                     const float* __restrict__ gw,
                                                     int* __restrict__ eos,
                                                     float* __restrict__ wos) {
  int wave = threadIdx.x >> 6, lane = threadIdx.x & 63;
  int n = blockIdx.x * 4 + wave;
  const float* xr = x + (size_t)n * DM;
  float acc[NE];
#pragma unroll
  for (int e = 0; e < NE; e++) acc[e] = 0.f;
  for (int d = lane; d < DM; d += 64) {
    float xv = xr[d];
#pragma unroll
    for (int e = 0; e < NE; e++) acc[e] += xv * gw[e * DM + d];
  }
#pragma unroll
  for (int e = 0; e < NE; e++) {
    float v = acc[e];
#pragma unroll
    for (int off = 32; off > 0; off >>= 1) v += __shfl_xor(v, off, 64);
    acc[e] = v;
  }
  if (lane == 0) {
    int i0 = 0;
    for (int e = 1; e < NE; e++) if (acc[e] > acc[i0]) i0 = e;
    int i1 = (i0 == 0) ? 1 : 0;
    for (int e = 0; e < NE; e++) { if (e == i0) continue; if (acc[e] > acc[i1]) i1 = e; }
    float e1 = expf(acc[i1] - acc[i0]);
    float w0 = 1.f / (1.f + e1);
    eos[2 * n] = i0;  eos[2 * n + 1] = i1;
    wos[2 * n] = w0;  wos[2 * n + 1] = 1.f - w0;
  }
}

// ---------------- deterministic counting sort: slots -> expert groups ----------------
__global__ __launch_bounds__(256) void build_groups_kernel(
    const int* __restrict__ eos, const float* __restrict__ wos,
    int* __restrict__ goff, int* __restrict__ tok_of_g, float* __restrict__ w_of_g) {
  __shared__ int pref[256][NE];   // per-thread per-expert counts -> exclusive prefix
  __shared__ int tot[NE];
  __shared__ int ebase[NE + 1];
  int t = threadIdx.x;
  int c[NE];
#pragma unroll
  for (int e = 0; e < NE; e++) c[e] = 0;
  for (int i = 0; i < NSLOT / 256; i++) {
    int e = eos[t * (NSLOT / 256) + i];
#pragma unroll
    for (int q = 0; q < NE; q++) if (e == q) c[q]++;
  }
#pragma unroll
  for (int e = 0; e < NE; e++) pref[t][e] = c[e];
  __syncthreads();
  if (t < NE) {
    int run = 0;
    for (int i = 0; i < 256; i++) { int v = pref[i][t]; pref[i][t] = run; run += v; }
    tot[t] = run;
  }
  __syncthreads();
  if (t == 0) {
    int o = 0;
    for (int e = 0; e < NE; e++) { ebase[e] = o; o += tot[e]; }
    ebase[NE] = o;
  }
  __syncthreads();
  int off[NE];
#pragma unroll
  for (int e = 0; e < NE; e++) off[e] = ebase[e] + pref[t][e];
  for (int i = 0; i < NSLOT / 256; i++) {
    int s = t * (NSLOT / 256) + i;
    int e = eos[s];
    int g = 0;
#pragma unroll
    for (int q = 0; q < NE; q++) if (e == q) { g = off[q]; off[q] = g + 1; }
    tok_of_g[g] = s >> 1;
    w_of_g[g] = wos[s];
  }
  if (t <= NE) goff[t] = ebase[t];
}

// ---------------- grouped GEMM, m97-style global_load_lds staging ----------------
// 128x128 tile, BK=32, 4 waves (2x2), per-wave 64x64 (4x4 of 16x16x32)
// MODE 0: A=xb gathered rows, epilogue gelu -> h (bf16)
// MODE 1: A=h contiguous rows, epilogue gate-weighted atomicAdd -> out (fp32)
template<int K, int NOUT, int MODE>
__global__ __launch_bounds__(256) void moe_gemm(
    const u16* __restrict__ A, const u16* __restrict__ Wt, const float* __restrict__ bias,
    const int* __restrict__ goff, const int* __restrict__ tok_of_g,
    const float* __restrict__ w_of_g,
    u16* __restrict__ Hout, float* __restrict__ Out) {
  int e = blockIdx.z;
  int gb = goff[e];
  int cntE = goff[e + 1] - gb;
  int m0 = blockIdx.y * 128;
  if (m0 >= cntE) return;
  int mvalid = cntE - m0; if (mvalid > 128) mvalid = 128;
  int gbase = gb + m0;
  int n0 = blockIdx.x * 128;
  int tid = threadIdx.x;
  int lane = tid & 63, wave = tid >> 6;

  __shared__ __align__(16) u16 As[128 * 32];   // 8 KB, no pad (global_load_lds layout)
  __shared__ __align__(16) u16 Bs[128 * 32];

  // staging: wave w writes chunk rows [w*16, w*16+16) and [64+w*16, ...)
  int sr = lane >> 2;            // 0..15 row within chunk
  int sc = (lane & 3) * 8;       // elem col offset (16B)
  int ra0 = wave * 16 + sr;
  int ra1 = 64 + wave * 16 + sr;
  int ca0 = (ra0 < mvalid) ? ra0 : (mvalid - 1);
  int ca1 = (ra1 < mvalid) ? ra1 : (mvalid - 1);
  const u16 *pa0, *pa1;
  if (MODE == 0) {
    pa0 = A + (size_t)tok_of_g[gbase + ca0] * K + sc;
    pa1 = A + (size_t)tok_of_g[gbase + ca1] * K + sc;
  } else {
    pa0 = A + (size_t)(gbase + ca0) * K + sc;
    pa1 = A + (size_t)(gbase + ca1) * K + sc;
  }
  const u16* wte = Wt + (size_t)e * NOUT * K;
  const u16* pb0 = wte + (size_t)(n0 + ra0) * K + sc;
  const u16* pb1 = wte + (size_t)(n0 + ra1) * K + sc;
  u16* ldsA0 = As + wave * 512;           // wave-uniform bases
  u16* ldsA1 = As + 2048 + wave * 512;
  u16* ldsB0 = Bs + wave * 512;
  u16* ldsB1 = Bs + 2048 + wave * 512;

  int wm = wave >> 1, wn = wave & 1;
  int lr = lane & 15, lk = (lane >> 4) * 8;

  floatx4 acc[4][4];
#pragma unroll
  for (int i = 0; i < 4; i++)
#pragma unroll
    for (int j = 0; j < 4; j++) acc[i][j] = (floatx4){0.f, 0.f, 0.f, 0.f};

  for (int k0 = 0; k0 < K; k0 += 32) {
    __syncthreads();
    async_cp16(pa0 + k0, ldsA0);
    async_cp16(pa1 + k0, ldsA1);
    async_cp16(pb0 + k0, ldsB0);
    async_cp16(pb1 + k0, ldsB1);
    __syncthreads();
    shortx8 af[4], bfr[4];
#pragma unroll
    for (int i = 0; i < 4; i++) {
      af[i]  = *(const shortx8*)&As[(wm * 64 + i * 16 + lr) * 32 + lk];
      bfr[i] = *(const shortx8*)&Bs[(wn * 64 + i * 16 + lr) * 32 + lk];
    }
#pragma unroll
    for (int i = 0; i < 4; i++)
#pragma unroll
      for (int j = 0; j < 4; j++)
        acc[i][j] = __builtin_amdgcn_mfma_f32_16x16x32_bf16(af[i], bfr[j], acc[i][j], 0, 0, 0);
  }

  const float* bp = bias + (size_t)e * NOUT + n0;
  if (MODE == 0) {
#pragma unroll
    for (int i = 0; i < 4; i++) {
      int rowb = wm * 64 + i * 16 + (lane >> 4) * 4;
#pragma unroll
      for (int r = 0; r < 4; r++) {
        int grow = rowb + r;
        if (grow < mvalid) {
          size_t base = (size_t)(gbase + grow) * NOUT + n0;
#pragma unroll
          for (int j = 0; j < 4; j++) {
            int col = wn * 64 + j * 16 + lr;
            float v = acc[i][j][r] + bp[col];
            v = 0.5f * v * (1.f + erff(v * 0.70710678118654752f));  // exact gelu
            Hout[base + col] = f2bf(v);
          }
        }
      }
    }
  } else {
#pragma unroll
    for (int i = 0; i < 4; i++) {
      int rowb = wm * 64 + i * 16 + (lane >> 4) * 4;
#pragma unroll
      for (int r = 0; r < 4; r++) {
        int grow = rowb + r;
        if (grow < mvalid) {
          int gi = gbase + grow;
          int t = tok_of_g[gi];
          float wg = w_of_g[gi];
          float* orow = Out + (size_t)t * DM + n0;
#pragma unroll
          for (int j = 0; j < 4; j++) {
            int col = wn * 64 + j * 16 + lr;
            atomicAdd(&orow[col], wg * (acc[i][j][r] + bp[col]));
          }
        }
      }
    }
  }
}

extern "C" void kernel_launch(void* const* d_in, const int* in_sizes, int n_in,
                              void* d_out, int out_size, void* d_ws, size_t ws_size,
                              hipStream_t stream) {
  const float* x  = (const float*)d_in[0];
  const float* gw = (const float*)d_in[1];
  const float* w1 = (const float*)d_in[2];
  const float* b1 = (const float*)d_in[3];
  const float* w2 = (const float*)d_in[4];
  const float* b2 = (const float*)d_in[5];
  float* out = (float*)d_out;
  char* ws = (char*)d_ws;

  // workspace layout (~142.8 MB): w2t reuses w1t region (dead after GEMM1)
  u16* xb = (u16*)(ws + 0);                       // 8 MB
  u16* wt = (u16*)(ws + 8388608);                 // 64 MB (w1t, then w2t)
  u16* h  = (u16*)(ws + 75497472);                // 64 MB
  char* meta = ws + 142606336;
  int*   eos      = (int*)(meta);
  int*   tok_of_g = (int*)(meta + 32768);
  float* wos      = (float*)(meta + 65536);
  float* w_of_g   = (float*)(meta + 98304);
  int*   goff     = (int*)(meta + 131072);

  hipMemsetAsync(out, 0, (size_t)NTOK * DM * 4, stream);

  cvt_x_kernel<<<NTOK * DM / 8 / 256, 256, 0, stream>>>(x, xb);
  transpose_kernel<DM, DH><<<dim3(DH / 64, DM / 256, NE), 256, 0, stream>>>(w1, wt);
  router_kernel<<<NTOK / 4, 256, 0, stream>>>(x, gw, eos, wos);
  build_groups_kernel<<<1, 256, 0, stream>>>(eos, wos, goff, tok_of_g, w_of_g);
  moe_gemm<DM, DH, 0><<<dim3(DH / 128, NTOK / 128, NE), 256, 0, stream>>>(
      xb, wt, b1, goff, tok_of_g, w_of_g, h, nullptr);
  transpose_kernel<DH, DM><<<dim3(DM / 64, DH / 256, NE), 256, 0, stream>>>(w2, wt);
  moe_gemm<DH, DM, 1><<<dim3(DM / 128, NTOK / 128, NE), 256, 0, stream>>>(
      h, wt, b2, goff, tok_of_g, w_of_g, nullptr, out);
}